// Round 4
// baseline (1129.700 us; speedup 1.0000x reference)
//
#include <hip/hip_runtime.h>
#include <hip/hip_fp16.h>
#include <math.h>

// BatchSpectralLoss: out = lambda_max(A^T A), A = 8192x4096 fp32 (k==1).
// T-step Lanczos; per step ONE pass over fp16 A. Each block owns a 16-row
// chunk held ENTIRELY in registers (16 x float4 of packed halves): dot phase
// and accumulate phase both run from registers -> A is read exactly once per
// step. Blocks write private partial-w slices (no contended atomics);
// reduce_finish sums them + applies the Lanczos recurrence. Tridiagonal
// solved by Sturm bisection in one wave.
//
// ws float layout: vb0/vb1/vb2 at 0/4096/8192 (rotating residuals),
// slots at 12288 (alpha[j]=slots[j], norm2[j]=slots[64+j]),
// partials at 16384 (P x 4096), Ah (fp16 copy) at byte offset 16 MiB.

#define NROWS 8192
#define NCOLS 4096
#define T_STEPS 16
#define CHUNKS 512          // 512 chunks x 16 rows
#define RPC 16              // rows per chunk

__global__ __launch_bounds__(256) void init_kernel(float* __restrict__ ws) {
    int i = blockIdx.x * 256 + threadIdx.x;   // 0..4095
    float* r1 = ws;
    float* r0 = ws + 4096;
    float* slots = ws + 12288;
    unsigned h = (unsigned)i * 2654435761u;
    h ^= h >> 16; h *= 2246822519u; h ^= h >> 13;
    r1[i] = (h & 1u) ? 0.015625f : -0.015625f;   // +-1/64, unit norm
    r0[i] = 0.f;
    if (i < 128) slots[i] = (i == 64 || i == 65) ? 1.f : 0.f;
}

__global__ __launch_bounds__(256) void convert_kernel(const float* __restrict__ A,
                                                      __half* __restrict__ Ah) {
    const float4* A4 = (const float4*)A;
    float2* O2 = (float2*)Ah;
    for (int i = blockIdx.x * 256 + threadIdx.x; i < (NROWS * NCOLS / 4); i += 2048 * 256) {
        float4 f = A4[i];
        union { float2 f2; __half2 h2[2]; } u;
        u.h2[0] = __halves2half2(__float2half_rn(f.x), __float2half_rn(f.y));
        u.h2[1] = __halves2half2(__float2half_rn(f.z), __float2half_rn(f.w));
        O2[i] = u.f2;
    }
}

// ---- fused B-matvec, fp16 A, register-resident chunk.
// 512 blocks x 512 thr (8 waves). Wave covers cols [wv*512, wv*512+512);
// lane owns 8 consecutive cols (one float4 of halves per row). Block owns
// rows [blockIdx.x*16, +16). A read exactly once (burst of 16 loads).
__global__ __launch_bounds__(512, 4) void bmv_f16(const __half* __restrict__ Ah,
                                                  const float* __restrict__ rc,
                                                  float* __restrict__ partials,
                                                  float* __restrict__ slots,
                                                  int j) {
    __shared__ float grid[8][16];
    int tid = threadIdx.x, lane = tid & 63, wv = tid >> 6;
    float inv = rsqrtf(fmaxf(slots[64 + j], 1e-30f));
    int colbase = wv * 512 + lane * 8;
    float vf[8];
    {
        const float4* r4 = (const float4*)(rc + colbase);
        float4 va = r4[0], vb = r4[1];
        vf[0] = va.x * inv; vf[1] = va.y * inv; vf[2] = va.z * inv; vf[3] = va.w * inv;
        vf[4] = vb.x * inv; vf[5] = vb.y * inv; vf[6] = vb.z * inv; vf[7] = vb.w * inv;
    }
    // ---- burst-load the whole 16-row slice into registers (16 x 16B in flight)
    const float4* Abase = (const float4*)(Ah + (size_t)blockIdx.x * RPC * NCOLS + colbase);
    float4 a[RPC];
#pragma unroll
    for (int r = 0; r < RPC; ++r) a[r] = Abase[r * (NCOLS / 8)];
    // ---- dot phase: sp[r] = partial (A_r . v) over this lane's 8 cols
    float sp[RPC];
#pragma unroll
    for (int r = 0; r < RPC; ++r) {
        union { float4 f4; __half2 h2[4]; } u;
        u.f4 = a[r];
        float2 p0 = __half22float2(u.h2[0]);
        float2 p1 = __half22float2(u.h2[1]);
        float2 p2 = __half22float2(u.h2[2]);
        float2 p3 = __half22float2(u.h2[3]);
        sp[r] = p0.x * vf[0] + p0.y * vf[1] + p1.x * vf[2] + p1.y * vf[3]
              + p2.x * vf[4] + p2.y * vf[5] + p3.x * vf[6] + p3.y * vf[7];
    }
    // ---- reduce each row's partial across the 64 lanes
#pragma unroll
    for (int r = 0; r < RPC; ++r) {
#pragma unroll
        for (int off = 32; off > 0; off >>= 1) sp[r] += __shfl_xor(sp[r], off);
    }
    if (lane == 0) {
#pragma unroll
        for (int r = 0; r < RPC; ++r) grid[wv][r] = sp[r];
    }
    __syncthreads();
    float sval = 0.f;
    if (lane < RPC) {
#pragma unroll
        for (int w8 = 0; w8 < 8; ++w8) sval += grid[w8][lane];
    }
    if (wv == 0) {   // alpha += sum_r s_r^2 : one atomic per block
        float p = (lane < RPC) ? sval * sval : 0.f;
#pragma unroll
        for (int off = 8; off > 0; off >>= 1) p += __shfl_xor(p, off);
        if (lane == 0) atomicAdd(&slots[j], p);
    }
    // ---- accumulate phase: w_c += s_r * A[r,c], straight from registers
    float wacc[8] = {0.f, 0.f, 0.f, 0.f, 0.f, 0.f, 0.f, 0.f};
#pragma unroll
    for (int r = 0; r < RPC; ++r) {
        float s = __shfl(sval, r);
        union { float4 f4; __half2 h2[4]; } u;
        u.f4 = a[r];
        float2 p0 = __half22float2(u.h2[0]);
        float2 p1 = __half22float2(u.h2[1]);
        float2 p2 = __half22float2(u.h2[2]);
        float2 p3 = __half22float2(u.h2[3]);
        wacc[0] += s * p0.x; wacc[1] += s * p0.y; wacc[2] += s * p1.x; wacc[3] += s * p1.y;
        wacc[4] += s * p2.x; wacc[5] += s * p2.y; wacc[6] += s * p3.x; wacc[7] += s * p3.y;
    }
    float4* pb = (float4*)(partials + (size_t)blockIdx.x * NCOLS + colbase);
    pb[0] = make_float4(wacc[0], wacc[1], wacc[2], wacc[3]);
    pb[1] = make_float4(wacc[4], wacc[5], wacc[6], wacc[7]);
}

// ---- fused B-matvec, fp32 A (fallback if ws too small for the fp16 copy).
__global__ __launch_bounds__(512, 4) void bmv_f32(const float* __restrict__ A,
                                                  const float* __restrict__ rc,
                                                  float* __restrict__ partials,
                                                  float* __restrict__ slots,
                                                  int j, int P) {
    __shared__ float grid[8][16];
    int tid = threadIdx.x, lane = tid & 63, wv = tid >> 6;
    float inv = rsqrtf(fmaxf(slots[64 + j], 1e-30f));
    float vf[8];
    {
        const float4* r4 = (const float4*)(rc + wv * 512);
        float4 va = r4[lane], vb = r4[64 + lane];
        vf[0] = va.x * inv; vf[1] = va.y * inv; vf[2] = va.z * inv; vf[3] = va.w * inv;
        vf[4] = vb.x * inv; vf[5] = vb.y * inv; vf[6] = vb.z * inv; vf[7] = vb.w * inv;
    }
    float wacc[8] = {0.f, 0.f, 0.f, 0.f, 0.f, 0.f, 0.f, 0.f};
    for (int chunk = blockIdx.x; chunk < CHUNKS; chunk += P) {
        __syncthreads();
        const float4* Abase = (const float4*)(A + (size_t)chunk * RPC * NCOLS + wv * 512);
        float sp[RPC];
#pragma unroll
        for (int r = 0; r < RPC; ++r) {
            float4 a0 = Abase[r * (NCOLS / 4) + lane];
            float4 a1 = Abase[r * (NCOLS / 4) + 64 + lane];
            sp[r] = a0.x * vf[0] + a0.y * vf[1] + a0.z * vf[2] + a0.w * vf[3]
                  + a1.x * vf[4] + a1.y * vf[5] + a1.z * vf[6] + a1.w * vf[7];
        }
#pragma unroll
        for (int r = 0; r < RPC; ++r) {
#pragma unroll
            for (int off = 32; off > 0; off >>= 1) sp[r] += __shfl_xor(sp[r], off);
        }
        if (lane == 0) {
#pragma unroll
            for (int r = 0; r < RPC; ++r) grid[wv][r] = sp[r];
        }
        __syncthreads();
        float sval = 0.f;
        if (lane < RPC) {
#pragma unroll
            for (int w8 = 0; w8 < 8; ++w8) sval += grid[w8][lane];
        }
        if (wv == 0) {
            float p = (lane < RPC) ? sval * sval : 0.f;
#pragma unroll
            for (int off = 8; off > 0; off >>= 1) p += __shfl_xor(p, off);
            if (lane == 0) atomicAdd(&slots[j], p);
        }
#pragma unroll
        for (int r = 0; r < RPC; ++r) {
            float s = __shfl(sval, r);
            float4 a0 = Abase[r * (NCOLS / 4) + lane];
            float4 a1 = Abase[r * (NCOLS / 4) + 64 + lane];
            wacc[0] += s * a0.x; wacc[1] += s * a0.y; wacc[2] += s * a0.z; wacc[3] += s * a0.w;
            wacc[4] += s * a1.x; wacc[5] += s * a1.y; wacc[6] += s * a1.z; wacc[7] += s * a1.w;
        }
    }
    float4* pb = (float4*)(partials + (size_t)blockIdx.x * NCOLS + wv * 512);
    pb[lane] = make_float4(wacc[0], wacc[1], wacc[2], wacc[3]);
    pb[64 + lane] = make_float4(wacc[4], wacc[5], wacc[6], wacc[7]);
}

// ---- sum P partials per column + Lanczos recurrence:
// r_{j+1} = w - alpha_j v_j - beta_{j-1} v_{j-1};  norm2[j+1] += ||r||^2.
__global__ __launch_bounds__(512) void reduce_finish(const float* __restrict__ partials,
                                                     float* __restrict__ wt,
                                                     const float* __restrict__ rc,
                                                     const float* __restrict__ rp,
                                                     float* __restrict__ slots,
                                                     int j, int P) {
    __shared__ float red[8][64];
    int tid = threadIdx.x, l = tid & 63, q = tid >> 6;
    int c = blockIdx.x * 64 + l;
    int nb = P >> 3;
    float s = 0.f;
    const float* p0 = partials + (size_t)q * nb * NCOLS + c;
    for (int b = 0; b < nb; ++b) s += p0[(size_t)b * NCOLS];
    red[q][l] = s;
    __syncthreads();
    if (tid < 64) {
        float w = 0.f;
#pragma unroll
        for (int qq = 0; qq < 8; ++qq) w += red[qq][tid];
        float a = slots[j];
        float n2j = fmaxf(slots[64 + j], 1e-30f);
        float n2m = fmaxf(slots[64 + j - 1], 1e-30f);
        float invj = rsqrtf(n2j);
        float cb = sqrtf(n2j / n2m);             // beta_{j-1}/||r_{j-1}||
        float rn = w - a * invj * rc[c] - cb * rp[c];
        wt[c] = rn;
        float p = rn * rn;
#pragma unroll
        for (int off = 32; off > 0; off >>= 1) p += __shfl_xor(p, off);
        if (tid == 0) atomicAdd(&slots[64 + j + 1], p);
    }
}

// ---- largest eigenvalue of t x t tridiagonal via Sturm bisection (1 wave).
__global__ void solve_kernel(const float* __restrict__ slots,
                             float* __restrict__ out, int t) {
    __shared__ float d_s[64], e2_s[64];
    int lane = threadIdx.x;
    d_s[lane] = (lane < t) ? slots[1 + lane] : 0.f;
    e2_s[lane] = (lane < t - 1) ? slots[64 + lane + 2] : 0.f;
    __syncthreads();
    float e_here = sqrtf(e2_s[lane]);
    float e_prev = (lane > 0) ? sqrtf(e2_s[lane - 1]) : 0.f;
    float d = d_s[lane];
    float gersh = (lane < t) ? d + e_here + e_prev : 0.f;
    float dmax = (lane < t) ? d : 0.f;
#pragma unroll
    for (int off = 32; off > 0; off >>= 1) {
        gersh = fmaxf(gersh, __shfl_xor(gersh, off));
        dmax = fmaxf(dmax, __shfl_xor(dmax, off));
    }
    float lo = dmax, hi = gersh + 1e-3f;
    for (int round = 0; round < 3; ++round) {
        float stepw = (hi - lo) * (1.f / 64.f);
        float x = lo + stepw * (lane + 1);
        double qv = 1.0;
        int cnt = 0;
        for (int i = 0; i < t; ++i) {
            double qi = (double)d_s[i] - (double)x - ((i > 0) ? (double)e2_s[i - 1] / qv : 0.0);
            if (fabs(qi) < 1e-300) qi = -1e-300;
            cnt += (qi < 0.0);
            qv = qi;
        }
        unsigned long long m = __ballot(cnt < t);
        if (m) {
            int h = 63 - __clzll(m);
            lo = lo + stepw * (h + 1);
            hi = lo + stepw;
        } else {
            hi = lo + stepw;
        }
    }
    if (lane == 0) out[0] = 0.5f * (lo + hi);
}

extern "C" void kernel_launch(void* const* d_in, const int* in_sizes, int n_in,
                              void* d_out, int out_size, void* d_ws, size_t ws_size,
                              hipStream_t stream) {
    const float* A = (const float*)d_in[0];
    float* out = (float*)d_out;
    float* ws = (float*)d_ws;
    float* vb[3] = {ws, ws + 4096, ws + 8192};
    float* slots = ws + 12288;
    float* partials = ws + 16384;
    __half* Ah = (__half*)((char*)d_ws + (size_t)16 * 1024 * 1024);

    const size_t need_f16 = (size_t)16 * 1024 * 1024 + sizeof(__half) * (size_t)NROWS * NCOLS;
    bool use_f16 = (ws_size >= need_f16);
    int P;
    if (use_f16) {
        P = 512;
    } else {
        size_t avail = (ws_size > 16384u * 4u) ? ws_size - 16384u * 4u : 0;
        int pmax = (int)(avail / ((size_t)NCOLS * 4));
        P = pmax >= 512 ? 512 : (pmax / 8) * 8;
        if (P < 8) P = 8;
    }

    init_kernel<<<16, 256, 0, stream>>>(ws);
    if (use_f16) convert_kernel<<<2048, 256, 0, stream>>>(A, Ah);

    const int T = T_STEPS;
    for (int j = 1; j <= T; ++j) {
        float* rc = vb[j % 3];
        float* rp = vb[(j + 2) % 3];
        float* wt = vb[(j + 1) % 3];
        if (use_f16)
            bmv_f16<<<CHUNKS, 512, 0, stream>>>(Ah, rc, partials, slots, j);
        else
            bmv_f32<<<P, 512, 0, stream>>>(A, rc, partials, slots, j, P);
        if (j < T)
            reduce_finish<<<64, 512, 0, stream>>>(partials, wt, rc, rp, slots, j, use_f16 ? 512 : P);
    }
    solve_kernel<<<1, 64, 0, stream>>>(slots, out, T);
}

// Round 5
// 844.310 us; speedup vs baseline: 1.3380x; 1.3380x over previous
//
#include <hip/hip_runtime.h>
#include <hip/hip_fp16.h>
#include <math.h>

// BatchSpectralLoss: out = lambda_max(A^T A), A = 8192x4096 fp32 (k==1).
// T-step Lanczos, fused one-pass B-matvec: block covers ALL 4096 cols
// (256 threads x 16 cols each, as two 8-col groups -> perfect coalescing),
// processes 8 rows/chunk x 2 grid-strided chunks. Row slice = 8 regs/thread
// (8 rows x 2 float4 of packed halves = 64 VGPRs, ~115 total: no spill).
// Only the 8 per-row dots need a reduce (shuffle + 1 LDS atomic per wave);
// the w-accumulate is per-thread register FMA (no reduce, no contention).
// Blocks write private partial-w (512 x 16 KB); two-stage coalesced reduce
// applies the Lanczos recurrence. Tridiagonal solved by Sturm bisection.
//
// ws float layout: vb0/vb1/vb2 at 0/4096/8192, slots at 12288
//   (alpha[j]=slots[j], norm2[j]=slots[64+j]), p2 at 16384 (32x4096),
//   partials at 262144 (512x4096). Ah (fp16 copy) at byte offset 16 MiB.

#define NROWS 8192
#define NCOLS 4096
#define T_STEPS 16
#define BMV_BLOCKS 512
#define RPC 8            // rows per chunk

__global__ __launch_bounds__(256) void init_kernel(float* __restrict__ ws) {
    int i = blockIdx.x * 256 + threadIdx.x;   // 0..4095
    float* r1 = ws;
    float* r0 = ws + 4096;
    float* slots = ws + 12288;
    unsigned h = (unsigned)i * 2654435761u;
    h ^= h >> 16; h *= 2246822519u; h ^= h >> 13;
    r1[i] = (h & 1u) ? 0.015625f : -0.015625f;   // +-1/64, unit norm
    r0[i] = 0.f;
    if (i < 128) slots[i] = (i == 64 || i == 65) ? 1.f : 0.f;
}

__global__ __launch_bounds__(256) void convert_kernel(const float* __restrict__ A,
                                                      __half* __restrict__ Ah) {
    const float4* A4 = (const float4*)A;
    float2* O2 = (float2*)Ah;
    for (int i = blockIdx.x * 256 + threadIdx.x; i < (NROWS * NCOLS / 4); i += 2048 * 256) {
        float4 f = A4[i];
        union { float2 f2; __half2 h2[2]; } u;
        u.h2[0] = __halves2half2(__float2half_rn(f.x), __float2half_rn(f.y));
        u.h2[1] = __halves2half2(__float2half_rn(f.z), __float2half_rn(f.w));
        O2[i] = u.f2;
    }
}

__device__ __forceinline__ void up8(const float4& p, float* f) {
    const __half2* h = (const __half2*)&p;
    float2 t0 = __half22float2(h[0]);
    float2 t1 = __half22float2(h[1]);
    float2 t2 = __half22float2(h[2]);
    float2 t3 = __half22float2(h[3]);
    f[0] = t0.x; f[1] = t0.y; f[2] = t1.x; f[3] = t1.y;
    f[4] = t2.x; f[5] = t2.y; f[6] = t3.x; f[7] = t3.y;
}

// Fused w = A^T(Av) partial + alpha. 512 blocks x 256 thr (4 waves).
// Thread owns cols [tid*8, tid*8+8) and [2048+tid*8, +8).
__global__ __launch_bounds__(256, 4) void bmv(const __half* __restrict__ Ah,
                                              const float* __restrict__ rc,
                                              float* __restrict__ partials,
                                              float* __restrict__ slots,
                                              int j) {
    __shared__ float s_lds[RPC];
    int tid = threadIdx.x, lane = tid & 63;
    float inv = rsqrtf(fmaxf(slots[64 + j], 1e-30f));
    int cA = tid * 8, cB = 2048 + tid * 8;
    float vA[8], vB[8];
    {
        const float4* r4 = (const float4*)(rc + cA);
        float4 x = r4[0], y = r4[1];
        vA[0] = x.x * inv; vA[1] = x.y * inv; vA[2] = x.z * inv; vA[3] = x.w * inv;
        vA[4] = y.x * inv; vA[5] = y.y * inv; vA[6] = y.z * inv; vA[7] = y.w * inv;
        const float4* s4 = (const float4*)(rc + cB);
        float4 z = s4[0], w = s4[1];
        vB[0] = z.x * inv; vB[1] = z.y * inv; vB[2] = z.z * inv; vB[3] = z.w * inv;
        vB[4] = w.x * inv; vB[5] = w.y * inv; vB[6] = w.z * inv; vB[7] = w.w * inv;
    }
    float wacc[16];
#pragma unroll
    for (int i = 0; i < 16; ++i) wacc[i] = 0.f;

#pragma unroll 1
    for (int ch = 0; ch < 2; ++ch) {
        int row0 = ch * 4096 + blockIdx.x * RPC;
        const __half* base = Ah + (size_t)row0 * NCOLS;
        float4 alo[RPC], ahi[RPC];
#pragma unroll
        for (int r = 0; r < RPC; ++r) {
            alo[r] = *(const float4*)(base + (size_t)r * NCOLS + cA);
            ahi[r] = *(const float4*)(base + (size_t)r * NCOLS + cB);
        }
        __syncthreads();                       // prior chunk's s_lds readers done
        if (tid < RPC) s_lds[tid] = 0.f;
        __syncthreads();
#pragma unroll
        for (int r = 0; r < RPC; ++r) {
            float f[8];
            up8(alo[r], f);
            float sp = f[0] * vA[0] + f[1] * vA[1] + f[2] * vA[2] + f[3] * vA[3]
                     + f[4] * vA[4] + f[5] * vA[5] + f[6] * vA[6] + f[7] * vA[7];
            up8(ahi[r], f);
            sp += f[0] * vB[0] + f[1] * vB[1] + f[2] * vB[2] + f[3] * vB[3]
                + f[4] * vB[4] + f[5] * vB[5] + f[6] * vB[6] + f[7] * vB[7];
#pragma unroll
            for (int off = 32; off > 0; off >>= 1) sp += __shfl_xor(sp, off);
            if (lane == 0) atomicAdd(&s_lds[r], sp);
        }
        __syncthreads();
        if (tid == 0) {                        // alpha += sum_r s_r^2
            float aa = 0.f;
#pragma unroll
            for (int r = 0; r < RPC; ++r) aa += s_lds[r] * s_lds[r];
            atomicAdd(&slots[j], aa);
        }
#pragma unroll
        for (int r = 0; r < RPC; ++r) {        // w += s_r * A_r  (pure per-thread)
            float s = s_lds[r];
            float f[8];
            up8(alo[r], f);
            wacc[0] += s * f[0]; wacc[1] += s * f[1]; wacc[2] += s * f[2]; wacc[3] += s * f[3];
            wacc[4] += s * f[4]; wacc[5] += s * f[5]; wacc[6] += s * f[6]; wacc[7] += s * f[7];
            up8(ahi[r], f);
            wacc[8] += s * f[0]; wacc[9] += s * f[1]; wacc[10] += s * f[2]; wacc[11] += s * f[3];
            wacc[12] += s * f[4]; wacc[13] += s * f[5]; wacc[14] += s * f[6]; wacc[15] += s * f[7];
        }
    }
    float* pb = partials + (size_t)blockIdx.x * NCOLS;
    float4* pa = (float4*)(pb + cA);
    pa[0] = make_float4(wacc[0], wacc[1], wacc[2], wacc[3]);
    pa[1] = make_float4(wacc[4], wacc[5], wacc[6], wacc[7]);
    float4* pc = (float4*)(pb + cB);
    pc[0] = make_float4(wacc[8], wacc[9], wacc[10], wacc[11]);
    pc[1] = make_float4(wacc[12], wacc[13], wacc[14], wacc[15]);
}

// Stage 1: 512 partial rows -> 32. Grid 512 = 16 col-slabs x 32 groups.
__global__ __launch_bounds__(256) void red1(const float* __restrict__ partials,
                                            float* __restrict__ p2) {
    int cb = blockIdx.x >> 5, g = blockIdx.x & 31;
    int col = cb * 256 + threadIdx.x;
    const float* p = partials + (size_t)(g * 16) * NCOLS + col;
    float s = 0.f;
#pragma unroll
    for (int k = 0; k < 16; ++k) s += p[(size_t)k * NCOLS];
    p2[(size_t)g * NCOLS + col] = s;
}

// Stage 2: 32 -> 1, fused Lanczos recurrence + ||r||^2 atomic. Grid 16.
__global__ __launch_bounds__(256) void red2(const float* __restrict__ p2,
                                            float* __restrict__ wt,
                                            const float* __restrict__ rc,
                                            const float* __restrict__ rp,
                                            float* __restrict__ slots,
                                            int j) {
    int tid = threadIdx.x;
    int col = blockIdx.x * 256 + tid;
    float w = 0.f;
#pragma unroll
    for (int g = 0; g < 32; ++g) w += p2[(size_t)g * NCOLS + col];
    float a = slots[j];
    float n2j = fmaxf(slots[64 + j], 1e-30f);
    float n2m = fmaxf(slots[64 + j - 1], 1e-30f);
    float invj = rsqrtf(n2j);
    float cb = sqrtf(n2j / n2m);               // beta_{j-1}/||r_{j-1}||
    float rn = w - a * invj * rc[col] - cb * rp[col];
    wt[col] = rn;
    float p = rn * rn;
#pragma unroll
    for (int off = 32; off > 0; off >>= 1) p += __shfl_xor(p, off);
    __shared__ float part[4];
    int lane = tid & 63, wq = tid >> 6;
    if (lane == 0) part[wq] = p;
    __syncthreads();
    if (tid == 0)
        atomicAdd(&slots[64 + j + 1], part[0] + part[1] + part[2] + part[3]);
}

// Largest eigenvalue of t x t tridiagonal via Sturm bisection (1 wave).
__global__ void solve_kernel(const float* __restrict__ slots,
                             float* __restrict__ out, int t) {
    __shared__ float d_s[64], e2_s[64];
    int lane = threadIdx.x;
    d_s[lane] = (lane < t) ? slots[1 + lane] : 0.f;
    e2_s[lane] = (lane < t - 1) ? slots[64 + lane + 2] : 0.f;
    __syncthreads();
    float e_here = sqrtf(e2_s[lane]);
    float e_prev = (lane > 0) ? sqrtf(e2_s[lane - 1]) : 0.f;
    float d = d_s[lane];
    float gersh = (lane < t) ? d + e_here + e_prev : 0.f;
    float dmax = (lane < t) ? d : 0.f;
#pragma unroll
    for (int off = 32; off > 0; off >>= 1) {
        gersh = fmaxf(gersh, __shfl_xor(gersh, off));
        dmax = fmaxf(dmax, __shfl_xor(dmax, off));
    }
    float lo = dmax, hi = gersh + 1e-3f;
    for (int round = 0; round < 3; ++round) {
        float stepw = (hi - lo) * (1.f / 64.f);
        float x = lo + stepw * (lane + 1);
        double qv = 1.0;
        int cnt = 0;
        for (int i = 0; i < t; ++i) {
            double qi = (double)d_s[i] - (double)x - ((i > 0) ? (double)e2_s[i - 1] / qv : 0.0);
            if (fabs(qi) < 1e-300) qi = -1e-300;
            cnt += (qi < 0.0);
            qv = qi;
        }
        unsigned long long m = __ballot(cnt < t);
        if (m) {
            int h = 63 - __clzll(m);
            lo = lo + stepw * (h + 1);
            hi = lo + stepw;
        } else {
            hi = lo + stepw;
        }
    }
    if (lane == 0) out[0] = 0.5f * (lo + hi);
}

extern "C" void kernel_launch(void* const* d_in, const int* in_sizes, int n_in,
                              void* d_out, int out_size, void* d_ws, size_t ws_size,
                              hipStream_t stream) {
    const float* A = (const float*)d_in[0];
    float* out = (float*)d_out;
    float* ws = (float*)d_ws;
    float* vb[3] = {ws, ws + 4096, ws + 8192};
    float* slots = ws + 12288;
    float* p2 = ws + 16384;           // 32 x 4096
    float* partials = ws + 262144;    // 512 x 4096, ends at 9 MiB
    __half* Ah = (__half*)((char*)d_ws + (size_t)16 * 1024 * 1024);

    init_kernel<<<16, 256, 0, stream>>>(ws);
    convert_kernel<<<2048, 256, 0, stream>>>(A, Ah);

    const int T = T_STEPS;
    for (int j = 1; j <= T; ++j) {
        float* rc = vb[j % 3];
        float* rp = vb[(j + 2) % 3];
        float* wt = vb[(j + 1) % 3];
        bmv<<<BMV_BLOCKS, 256, 0, stream>>>(Ah, rc, partials, slots, j);
        if (j < T) {
            red1<<<512, 256, 0, stream>>>(partials, p2);
            red2<<<16, 256, 0, stream>>>(p2, wt, rc, rp, slots, j);
        }
    }
    solve_kernel<<<1, 64, 0, stream>>>(slots, out, T);
}